// Round 6
// baseline (127.352 us; speedup 1.0000x reference)
//
#include <hip/hip_runtime.h>
#include <hip/hip_bf16.h>

typedef __attribute__((ext_vector_type(4)))  float          f32x4;
typedef __attribute__((ext_vector_type(16))) float          f32x16;
typedef __attribute__((ext_vector_type(8)))  short          bf16x8;
typedef __attribute__((ext_vector_type(8)))  unsigned short u16x8;

#define Cc 512
#define Vv 512
#define BM 128
#define NTILE 1250   // 160000 / 128

// W2: bf16 W in 32x32x16-MFMA B-fragment order.
// frag (vg = v>>5, ks = k>>4); lane = (v&31) + 32*((k>>3)&1); elem = k&7
// index = (vg*32 + ks)*512 + lane*8 + elem
__device__ unsigned short g_W2[Vv * Cc];
__device__ float g_ta[1600 * Cc];
__device__ float g_tp[400 * Cc];

__device__ __forceinline__ unsigned short f2bf(float f) {
    unsigned u = __float_as_uint(f);
    unsigned r = 0x7FFFu + ((u >> 16) & 1u);
    return (unsigned short)((u + r) >> 16);
}

__device__ __forceinline__ float fast_tanh(float x) {
    float e = __expf(2.0f * x);
    return 1.0f - 2.0f * __builtin_amdgcn_rcpf(e + 1.0f);
}

// blocks [0,128) -> W2 swizzle; [128,528) -> tanh(enc); [528,628) -> tanh(pred)
__global__ __launch_bounds__(256) void prep_kernel(
    const float* __restrict__ W, const float* __restrict__ enc,
    const float* __restrict__ pred)
{
    const int b = blockIdx.x;
    if (b < 128) {
        int gid = b * 256 + threadIdx.x;    // 0..32767, 8 k-elems each
        int v = gid >> 6;
        int k = (gid & 63) * 8;
        f32x4 a = *(const f32x4*)(W + v * Cc + k);
        f32x4 c = *(const f32x4*)(W + v * Cc + k + 4);
        u16x8 o;
#pragma unroll
        for (int j = 0; j < 4; ++j) {
            o[j]     = f2bf(a[j]);
            o[4 + j] = f2bf(c[j]);
        }
        int frag = (v >> 5) * 32 + (k >> 4);
        int lane = (v & 31) + 32 * ((k >> 3) & 1);
        *(u16x8*)(&g_W2[frag * 512 + lane * 8]) = o;
    } else if (b < 528) {
        int gid = (b - 128) * 256 + threadIdx.x;
        f32x4 a = *(const f32x4*)(enc + gid * 8);
        f32x4 c = *(const f32x4*)(enc + gid * 8 + 4);
        f32x4 o0, o1;
#pragma unroll
        for (int j = 0; j < 4; ++j) { o0[j] = fast_tanh(a[j]); o1[j] = fast_tanh(c[j]); }
        *(f32x4*)(g_ta + gid * 8)     = o0;
        *(f32x4*)(g_ta + gid * 8 + 4) = o1;
    } else {
        int gid = (b - 528) * 256 + threadIdx.x;
        f32x4 a = *(const f32x4*)(pred + gid * 8);
        f32x4 c = *(const f32x4*)(pred + gid * 8 + 4);
        f32x4 o0, o1;
#pragma unroll
        for (int j = 0; j < 4; ++j) { o0[j] = fast_tanh(a[j]); o1[j] = fast_tanh(c[j]); }
        *(f32x4*)(g_tp + gid * 8)     = o0;
        *(f32x4*)(g_tp + gid * 8 + 4) = o1;
    }
}

__global__ __launch_bounds__(512, 2) void joiner_main(
    const float* __restrict__ bias,  // (512,)
    float* __restrict__ out)         // (160000, 512)
{
    __shared__ unsigned short As[BM * Cc];   // 128 KB, XOR-swizzled rows

    const int tid = threadIdx.x;

    // ---- bijective XCD-chunked tile remap (8 XCDs, 1250 tiles; q=156,r=2) ----
    const int xcd  = blockIdx.x & 7;
    const int idx  = blockIdx.x >> 3;
    const int tile = (xcd < 2 ? xcd * 157 : 2 * 157 + (xcd - 2) * 156) + idx;

    // ---- stage: A = tanh(enc+pred) via tanh-sum identity -> bf16 LDS ----
    {
        const int sr = tid >> 2;         // 0..127 (tile row)
        const int sq = tid & 3;          // k slot
        const int m  = tile * BM + sr;
        const int et = m / 100;
        const int u  = m - et * 100;
        const int bb = m / 40000;
        const int pr = bb * 100 + u;
        const float* taP = g_ta + et * Cc;
        const float* tpP = g_tp + pr * Cc;
        char* asB = (char*)As;
        const int swz = (sr & 7) << 4;
#pragma unroll
        for (int c = 0; c < 16; ++c) {
            const int k0 = sq * 8 + c * 32;     // bank-spread interleave
            f32x4 a0 = *(const f32x4*)(taP + k0);
            f32x4 a1 = *(const f32x4*)(taP + k0 + 4);
            f32x4 p0 = *(const f32x4*)(tpP + k0);
            f32x4 p1 = *(const f32x4*)(tpP + k0 + 4);
            u16x8 o;
#pragma unroll
            for (int j = 0; j < 4; ++j) {
                float n0 = a0[j] + p0[j];
                float d0 = __builtin_fmaf(a0[j], p0[j], 1.0f);
                o[j] = f2bf(n0 * __builtin_amdgcn_rcpf(d0));
                float n1 = a1[j] + p1[j];
                float d1 = __builtin_fmaf(a1[j], p1[j], 1.0f);
                o[4 + j] = f2bf(n1 * __builtin_amdgcn_rcpf(d1));
            }
            int byte = sr * 1024 + k0 * 2;
            *(u16x8*)(asB + (byte ^ swz)) = o;
        }
    }

    // ---- compute setup; first B-fragments issued BEFORE the barrier ----
    const int lane  = tid & 63;
    const int w     = tid >> 6;          // wave -> V slice [w*64, (w+1)*64)
    const int lrow  = lane & 31;         // A-row / B-col within 32-block
    const int lksel = lane >> 5;         // selects k half (8 elems)

    // wave's W2 base: vg = w*2 + cj, fragment (vg*32 + ks), 1KB each
    const unsigned short* wb = &g_W2[(w * 2) * 32 * 512];
    const int lby = lane * 16;           // byte offset of this lane in a fragment

    bf16x8 bcur[2], bnx[2];
#pragma unroll
    for (int cj = 0; cj < 2; ++cj)
        bcur[cj] = *(const bf16x8*)((const char*)wb + (cj * 32 + 0) * 1024 + lby);

    __syncthreads();   // only barrier

    f32x16 acc[4][2];
#pragma unroll
    for (int i = 0; i < 4; ++i)
#pragma unroll
        for (int j = 0; j < 2; ++j)
            acc[i][j] = (f32x16)(0.0f);

    const char* asB = (const char*)As;
    const int aswz = (lrow & 7) << 4;    // row&7 == lrow&7 (ri*32 doesn't touch low bits)

#pragma unroll 2
    for (int ks = 0; ks < 32; ++ks) {
        if (ks < 31) {
#pragma unroll
            for (int cj = 0; cj < 2; ++cj)
                bnx[cj] = *(const bf16x8*)((const char*)wb + (cj * 32 + ks + 1) * 1024 + lby);
        }
        bf16x8 af[4];
#pragma unroll
        for (int ri = 0; ri < 4; ++ri) {
            int row  = ri * 32 + lrow;
            int byte = row * 1024 + ks * 32 + lksel * 16;
            af[ri] = *(const bf16x8*)(asB + (byte ^ aswz));
        }
#pragma unroll
        for (int ri = 0; ri < 4; ++ri)
#pragma unroll
            for (int cj = 0; cj < 2; ++cj)
                acc[ri][cj] = __builtin_amdgcn_mfma_f32_32x32x16_bf16(
                    af[ri], bcur[cj], acc[ri][cj], 0, 0, 0);
#pragma unroll
        for (int cj = 0; cj < 2; ++cj) bcur[cj] = bnx[cj];
    }

    // ---- epilogue: 32x32 C/D layout col=lane&31, row=(q&3)+8*(q>>2)+4*(lane>>5) ----
    float bia[2];
#pragma unroll
    for (int cj = 0; cj < 2; ++cj) bia[cj] = bias[w * 64 + cj * 32 + lrow];
#pragma unroll
    for (int ri = 0; ri < 4; ++ri) {
#pragma unroll
        for (int q = 0; q < 16; ++q) {
            int r   = ri * 32 + (q & 3) + 8 * (q >> 2) + 4 * lksel;
            int row = tile * BM + r;
            float* op = out + row * Vv + w * 64 + lrow;
#pragma unroll
            for (int cj = 0; cj < 2; ++cj)
                __builtin_nontemporal_store(acc[ri][cj][q] + bia[cj], op + cj * 32);
        }
    }
}

extern "C" void kernel_launch(void* const* d_in, const int* in_sizes, int n_in,
                              void* d_out, int out_size, void* d_ws, size_t ws_size,
                              hipStream_t stream) {
    const float* enc  = (const float*)d_in[0];
    const float* pred = (const float*)d_in[1];
    const float* W    = (const float*)d_in[2];
    const float* bias = (const float*)d_in[3];
    float* out        = (float*)d_out;

    prep_kernel<<<628, 256, 0, stream>>>(W, enc, pred);
    joiner_main<<<NTILE, 512, 0, stream>>>(bias, out);
}